// Round 4
// baseline (438.897 us; speedup 1.0000x reference)
//
#include <hip/hip_runtime.h>
#include <cstdint>
#include <cstddef>

// Problem constants: B=4, T=2048, H=1024, NH=16, HD=64, FF=4096, M=B*T=8192
typedef unsigned short u16;
typedef __attribute__((ext_vector_type(8))) __bf16 bf16x8;
typedef __attribute__((ext_vector_type(4))) __bf16 bf16x4;
typedef __attribute__((ext_vector_type(4))) float f32x4;
typedef __attribute__((ext_vector_type(4))) u16 u16x4;

#define MFMA(a, b, c) __builtin_amdgcn_mfma_f32_16x16x32_bf16((a), (b), (c), 0, 0, 0)

__device__ __forceinline__ u16 f2b(float f) {  // native RNE cvt (1-2 ops)
  union { __bf16 h; u16 u; } v;
  v.h = (__bf16)f;
  return v.u;
}

__device__ __forceinline__ void gld16(const void* g, void* l) {
  __builtin_amdgcn_global_load_lds(
      (__attribute__((address_space(1))) void*)(void*)(g),
      (__attribute__((address_space(3))) void*)(l), 16, 0, 0);
}

// Fragment-ordered layouts (per head, 131072 u16 = 2048x64):
// Q/K: element (t, hd): chunk ((t>>4)*2 + (hd>>5)), lane ((hd>>3)&3)*16 + (t&15),
//      byte-slot hd&7. MFMA lane l reads its 16B at chunk_base + l*16B.
__device__ __forceinline__ size_t qk_off(int t, int hd) {
  return (size_t)((((t >> 4) * 2 + (hd >> 5)) * 512)
                  + ((((hd >> 3) & 3) * 16 + (t & 15)) * 8) + (hd & 7));
}
// V: keys kk-permuted within 64-groups (kk = (t&15)*4 + ((t>>4)&3)) to match the
//    P-tile LDS packing; fragment order for PV B-operand reads.
__device__ __forceinline__ size_t v_off(int t, int hd) {
  int kk = ((t & 15) << 2) | ((t >> 4) & 3);
  return (size_t)(((t >> 6) * 4096)
                  + (((hd >> 4) * 2 + (kk >> 5)) * 512)
                  + ((((kk >> 3) & 3) * 16 + (hd & 15)) * 8) + (kk & 7));
}

// ---------------------------------------------------------------------------
// elementwise fp32 -> bf16 (vectorized x4)
__global__ void xconv(const float* __restrict__ in, u16* __restrict__ out, int n) {
  int i = (blockIdx.x * blockDim.x + threadIdx.x) * 4;
  if (i >= n) return;
  float4 v = *(const float4*)(in + i);
  u16x4 o;
  o[0] = f2b(v.x); o[1] = f2b(v.y); o[2] = f2b(v.z); o[3] = f2b(v.w);
  *(u16x4*)(out + i) = o;
}

// ---------------------------------------------------------------------------
// All weight transposes in ONE launch. W [K,N] fp32 -> Wt [N,K] bf16.
__global__ void wtrans_all(const float* __restrict__ Wq, const float* __restrict__ Wk,
                           const float* __restrict__ Wv, const float* __restrict__ W1,
                           const float* __restrict__ W2, u16* __restrict__ Wqkvt,
                           u16* __restrict__ W1t, u16* __restrict__ W2t) {
  __shared__ float tile[32][33];
  int blk = blockIdx.x;
  const float* W;
  u16* Wt;
  int Kd, Nd, nx;
  if (blk < 3072) {
    int s = blk >> 10;
    blk &= 1023;
    W = (s == 0) ? Wq : (s == 1) ? Wk : Wv;
    Wt = Wqkvt + (size_t)s * 1048576;
    Kd = 1024; Nd = 1024; nx = 32;
  } else if (blk < 7168) {
    blk -= 3072; W = W1; Wt = W1t; Kd = 1024; Nd = 4096; nx = 128;
  } else {
    blk -= 7168; W = W2; Wt = W2t; Kd = 4096; Nd = 1024; nx = 32;
  }
  int n0 = (blk % nx) * 32, k0 = (blk / nx) * 32;
  int tx = threadIdx.x, ty = threadIdx.y;
#pragma unroll
  for (int i = 0; i < 4; i++)
    tile[ty + i * 8][tx] = W[(size_t)(k0 + ty + i * 8) * Nd + n0 + tx];
  __syncthreads();
#pragma unroll
  for (int i = 0; i < 4; i++)
    Wt[(size_t)(n0 + ty + i * 8) * Kd + k0 + tx] = f2b(tile[tx][ty + i * 8]);
}

// ---------------------------------------------------------------------------
// 256x256 double-buffered barrier-light GEMM ("big"). BK=64, 8 waves as
// 2M x 4N, wave tile 128x64 (acc[8][4]). The wave-tile shape sets the
// MFMA:ds_read ratio: per K-tile per CU, 192 ds_read_b128 (2304 cyc port)
// vs 512 MFMA (2483 cyc matrix) -> matrix-dominant (the 64x64-wave variant
// was port-bound at 1536 vs 1241). LDS 128 KiB = 2 x (A 32K + B 32K).
// Per K-tile (NO intra-tile barriers; both passes read stable buf `cur`):
//   stage A(t+1) -> read af0/bf0 (12x b128) -> 32 MFMA (pass 0, overlaps
//   pass-1 reads via compiler lgkmcnt) -> stage B(t+1) -> read af1/bf1 ->
//   32 MFMA (pass 1) -> vmcnt(0) -> s_barrier.
// The vmcnt(0) waits on loads issued 1200-2400 cyc earlier (>> HBM latency):
// near-free drain. Buffer hazards: overwrite of buf[cur] by tile t+1's
// staging is gated by this barrier (all waves' reads complete before their
// last MFMA); buf[nxt] completeness is gated by vmcnt(0)+barrier.
// XOR-swizzled LDS both sides (conflict-free b128 reads, measured 0).
// XCD mapping: xcd owns bm in [4x,4x+4), bn walked in chunks of 4
// (bijective for nbm=32, nbn%4==0); concurrent L2 window ~4-6MB.
// MODE 2: bf16 out = gelu(v)   MODE 4: fused QKV scatter (frag-order Q/K/V)
template <int MODE>
__global__ __launch_bounds__(512, 2) void gemm_big(
    const u16* __restrict__ A, const u16* __restrict__ Bt,
    const float* __restrict__ b0, const float* __restrict__ b1,
    const float* __restrict__ b2, void* __restrict__ outp,
    int N, int K, float scale) {
  __shared__ __attribute__((aligned(16))) u16 As_[2][16384];
  __shared__ __attribute__((aligned(16))) u16 Bs_[2][16384];
  const int tid = threadIdx.x;
  const int wid = tid >> 6, lane = tid & 63;
  const int g = lane >> 4, r = lane & 15;

  // XCD-aware mapping: xcd = blk&7 owns bm rows [4*xcd, 4*xcd+4), bn in
  // chunks of 4. Bijective for grid = 32 * nbn, nbn % 4 == 0.
  const int xcd = blockIdx.x & 7;
  const int ii = blockIdx.x >> 3;
  const int c4 = ii >> 4, w = ii & 15;
  const int bm = xcd * 4 + (w >> 2);
  const int bn = c4 * 4 + (w & 3);

  const int wrow = (wid >> 2) * 128;  // 2 M-waves (128 rows each)
  const int wcol = (wid & 3) * 64;    // 4 N-waves (64 cols each)

  const int ko0 = ((0 * 4 + g) ^ (r & 7)) * 8;
  const int ko1 = ((1 * 4 + g) ^ (r & 7)) * 8;

  // per-thread staging source offsets (u16 elements); add t*64 per K-tile.
  // LDS chunk cc = row*8 + j holds global k-chunk j^(row&7) (XOR swizzle).
  size_t aOff[4], bOff[4];
#pragma unroll
  for (int i4 = 0; i4 < 4; i4++) {
    int cc = i4 * 512 + tid, row = cc >> 3;
    int js = ((cc & 7) ^ (row & 7)) * 8;
    aOff[i4] = (size_t)(bm * 256 + row) * K + js;
    bOff[i4] = (size_t)(bn * 256 + row) * K + js;
  }

  f32x4 acc[8][4];
  const f32x4 zero4 = {0.f, 0.f, 0.f, 0.f};
#pragma unroll
  for (int i = 0; i < 8; i++)
#pragma unroll
    for (int j = 0; j < 4; j++) acc[i][j] = zero4;

  // prologue: stage tile 0 into buffer 0
#pragma unroll
  for (int i4 = 0; i4 < 4; i4++) {
    gld16(A + aOff[i4], &As_[0][(i4 * 512 + tid) * 8]);
    gld16(Bt + bOff[i4], &Bs_[0][(i4 * 512 + tid) * 8]);
  }
  asm volatile("s_waitcnt vmcnt(0)" ::: "memory");
  __builtin_amdgcn_s_barrier();

  const int KT = K >> 6;
  int cur = 0;
  for (int t = 0; t < KT; ++t) {
    const u16* as = As_[cur];
    const u16* bs = Bs_[cur];
    const int nxt = cur ^ 1;
    const bool more = (t + 1) < KT;
    const size_t k1 = (size_t)(t + 1) * 64;

    // stage A(t+1) early (into buf[nxt]; safe after last tile's barrier)
    if (more) {
#pragma unroll
      for (int i4 = 0; i4 < 4; i4++)
        gld16(A + aOff[i4] + k1, &As_[nxt][(i4 * 512 + tid) * 8]);
    }

    // ---- pass 0 (k-half 0) ----
    {
      bf16x8 af[8], bf[4];
#pragma unroll
      for (int mt = 0; mt < 8; mt++)
        af[mt] = *(const bf16x8*)&as[(wrow + mt * 16 + r) * 64 + ko0];
#pragma unroll
      for (int nt = 0; nt < 4; nt++)
        bf[nt] = *(const bf16x8*)&bs[(wcol + nt * 16 + r) * 64 + ko0];
#pragma unroll
      for (int mt = 0; mt < 8; mt++)
#pragma unroll
        for (int nt = 0; nt < 4; nt++)
          acc[mt][nt] = MFMA(af[mt], bf[nt], acc[mt][nt]);
    }

    // stage B(t+1) mid-tile
    if (more) {
#pragma unroll
      for (int i4 = 0; i4 < 4; i4++)
        gld16(Bt + bOff[i4] + k1, &Bs_[nxt][(i4 * 512 + tid) * 8]);
    }

    // ---- pass 1 (k-half 1) ----
    {
      bf16x8 af[8], bf[4];
#pragma unroll
      for (int mt = 0; mt < 8; mt++)
        af[mt] = *(const bf16x8*)&as[(wrow + mt * 16 + r) * 64 + ko1];
#pragma unroll
      for (int nt = 0; nt < 4; nt++)
        bf[nt] = *(const bf16x8*)&bs[(wcol + nt * 16 + r) * 64 + ko1];
#pragma unroll
      for (int mt = 0; mt < 8; mt++)
#pragma unroll
        for (int nt = 0; nt < 4; nt++)
          acc[mt][nt] = MFMA(af[mt], bf[nt], acc[mt][nt]);
    }

    if (more) {
      // drain this tile's staging (issued 1200-2400 cyc ago: near-free),
      // then release buffers for the swap.
      asm volatile("s_waitcnt vmcnt(0)" ::: "memory");
      __builtin_amdgcn_s_barrier();
    }
    cur = nxt;
  }

  // epilogue: C[row][col], col = r (+16*nt), row = g*4 + q (+16*mt)
#pragma unroll
  for (int mt = 0; mt < 8; mt++) {
#pragma unroll
    for (int nt = 0; nt < 4; nt++) {
      int col = bn * 256 + wcol + nt * 16 + r;
      float bv;
      if (MODE == 4) {
        int sec = col >> 10, hcol = col & 1023;  // sec is block-uniform
        bv = (sec == 0) ? b0[hcol] : (sec == 1) ? b1[hcol] : b2[hcol];
      } else {
        bv = b0[col];
      }
#pragma unroll
      for (int q = 0; q < 4; q++) {
        int row = bm * 256 + wrow + mt * 16 + g * 4 + q;
        float v = acc[mt][nt][q] + bv;
        if (MODE == 2) {
          const float c1 = -2.3025850929940457f;
          const float c2 = c1 * 0.044715f;
          float t2 = v * v;
          float z = v * (c1 + c2 * t2);
          float sg = 1.0f / (1.0f + __builtin_amdgcn_exp2f(z));
          ((u16*)outp)[(size_t)row * N + col] = f2b(v * sg);
        } else if (MODE == 4) {
          int sec = col >> 10, hcol = col & 1023;
          int head = hcol >> 6, hd = hcol & 63;
          int bb = row >> 11, tt = row & 2047;
          size_t hbase = ((size_t)bb * 16 + head) * 131072;
          u16* qout = (u16*)outp;
          if (sec == 0) {
            qout[hbase + qk_off(tt, hd)] = f2b(v * scale);
          } else if (sec == 1) {
            (qout + 8388608)[hbase + qk_off(tt, hd)] = f2b(v);
          } else {
            (qout + 16777216)[hbase + v_off(tt, hd)] = f2b(v);
          }
        }
      }
    }
  }
}

// ---------------------------------------------------------------------------
// 256x128 3-buffer counted-vmcnt GEMM, barrier-light K-loop (kept for MLP2,
// whose N=1024 is too narrow for 256-wide tiles: 256x128 -> 256 blocks =
// exactly 1/CU). BK=64, 8 waves as 4M x 2N (64x64/wave, acc[4][4]).
// LDS 144 KiB = 3 x (A 32K + B 16K). See round-3 notes; MODE 3 only.
template <int MODE>
__global__ __launch_bounds__(512, 2) void gemm256(
    const u16* __restrict__ A, const u16* __restrict__ Bt,
    const float* __restrict__ b0, void* __restrict__ outp,
    const float* __restrict__ resid, int N, int K) {
  __shared__ __attribute__((aligned(16))) u16 As_[3][16384];
  __shared__ __attribute__((aligned(16))) u16 Bs_[3][8192];
  const int tid = threadIdx.x;
  const int wid = tid >> 6, lane = tid & 63;
  const int g = lane >> 4, r = lane & 15;

  // XCD-aware 2-D mapping (bijective for grid = 32 * nbn, nbn % 8 == 0)
  const int xcd = blockIdx.x & 7;
  const int ii = blockIdx.x >> 3;
  const int bm = xcd * 4 + ((ii & 31) >> 3);
  const int bn = (ii >> 5) * 8 + (ii & 7);

  const int wrow = (wid >> 1) * 64;   // 4 M-waves
  const int wcol = (wid & 1) * 64;    // 2 N-waves

  const int ko0 = ((0 * 4 + g) ^ (r & 7)) * 8;
  const int ko1 = ((1 * 4 + g) ^ (r & 7)) * 8;

  size_t aOff[4], bOff[2];
#pragma unroll
  for (int i4 = 0; i4 < 4; i4++) {
    int cc = i4 * 512 + tid, row = cc >> 3;
    int js = ((cc & 7) ^ (row & 7)) * 8;
    aOff[i4] = (size_t)(bm * 256 + row) * K + js;
  }
#pragma unroll
  for (int i2 = 0; i2 < 2; i2++) {
    int cc = i2 * 512 + tid, row = cc >> 3;
    int js = ((cc & 7) ^ (row & 7)) * 8;
    bOff[i2] = (size_t)(bn * 128 + row) * K + js;
  }

  f32x4 acc[4][4];
  const f32x4 zero4 = {0.f, 0.f, 0.f, 0.f};
#pragma unroll
  for (int i = 0; i < 4; i++)
#pragma unroll
    for (int j = 0; j < 4; j++) acc[i][j] = zero4;

  // prologue: stage tiles 0 and 1; wait for tile 0 only (tile 1 in flight)
#pragma unroll
  for (int i4 = 0; i4 < 4; i4++) gld16(A + aOff[i4], &As_[0][(i4 * 512 + tid) * 8]);
#pragma unroll
  for (int i2 = 0; i2 < 2; i2++) gld16(Bt + bOff[i2], &Bs_[0][(i2 * 512 + tid) * 8]);
#pragma unroll
  for (int i4 = 0; i4 < 4; i4++) gld16(A + aOff[i4] + 64, &As_[1][(i4 * 512 + tid) * 8]);
#pragma unroll
  for (int i2 = 0; i2 < 2; i2++) gld16(Bt + bOff[i2] + 64, &Bs_[1][(i2 * 512 + tid) * 8]);
  asm volatile("s_waitcnt vmcnt(6)" ::: "memory");
  __builtin_amdgcn_s_barrier();

  const int KT = K >> 6;
  int cur = 0;
  for (int t = 0; t < KT; ++t) {
    const u16* as = As_[cur];
    const u16* bs = Bs_[cur];
    const int stg = (cur == 0) ? 2 : cur - 1;  // (t+2)%3
    const bool more = (t + 2) < KT;
    const size_t k2 = (size_t)(t + 2) * 64;

    bf16x8 af0[4], bf0[4], af1[4], bf1[4];
#pragma unroll
    for (int mt = 0; mt < 4; mt++) {
      af0[mt] = *(const bf16x8*)&as[(wrow + mt * 16 + r) * 64 + ko0];
      af1[mt] = *(const bf16x8*)&as[(wrow + mt * 16 + r) * 64 + ko1];
    }
#pragma unroll
    for (int nt = 0; nt < 4; nt++) {
      bf0[nt] = *(const bf16x8*)&bs[(wcol + nt * 16 + r) * 64 + ko0];
      bf1[nt] = *(const bf16x8*)&bs[(wcol + nt * 16 + r) * 64 + ko1];
    }

    if (more) {
#pragma unroll
      for (int i4 = 0; i4 < 4; i4++)
        gld16(A + aOff[i4] + k2, &As_[stg][(i4 * 512 + tid) * 8]);
#pragma unroll
      for (int i2 = 0; i2 < 2; i2++)
        gld16(Bt + bOff[i2] + k2, &Bs_[stg][(i2 * 512 + tid) * 8]);
    }

#pragma unroll
    for (int mt = 0; mt < 4; mt++)
#pragma unroll
      for (int nt = 0; nt < 4; nt++)
        acc[mt][nt] = MFMA(af0[mt], bf0[nt], acc[mt][nt]);
#pragma unroll
    for (int mt = 0; mt < 4; mt++)
#pragma unroll
      for (int nt = 0; nt < 4; nt++)
        acc[mt][nt] = MFMA(af1[mt], bf1[nt], acc[mt][nt]);

    if (t + 1 < KT) {
      if (more) asm volatile("s_waitcnt vmcnt(6)" ::: "memory");
      else      asm volatile("s_waitcnt vmcnt(0)" ::: "memory");
    }
    __builtin_amdgcn_s_barrier();
    cur = (cur == 2) ? 0 : cur + 1;
  }

  // epilogue
#pragma unroll
  for (int mt = 0; mt < 4; mt++) {
#pragma unroll
    for (int nt = 0; nt < 4; nt++) {
      int col = bn * 128 + wcol + nt * 16 + r;
      float bv = b0[col];
#pragma unroll
      for (int q = 0; q < 4; q++) {
        int row = bm * 256 + wrow + mt * 16 + g * 4 + q;
        float v = acc[mt][nt][q] + bv;
        if (MODE == 3) {
          ((float*)outp)[(size_t)row * N + col] = v + resid[(size_t)row * N + col];
        }
      }
    }
  }
}

// ---------------------------------------------------------------------------
// Flash attention v4 (unchanged). Causal, Q pre-scaled by log2e/32.
__global__ __launch_bounds__(256) void attn_kernel(
    const u16* __restrict__ Q, const u16* __restrict__ Kc,
    const u16* __restrict__ Vt, const float* __restrict__ x,
    float* __restrict__ x1, u16* __restrict__ xb1) {
  const int bh = blockIdx.x & 63;
  const int slot = blockIdx.x >> 6;
  const int tid = threadIdx.x;
  const int wid = tid >> 6, lane = tid & 63;
  const int g = lane >> 4, c = lane & 15;
  const u16* Qh = Q + (size_t)bh * 131072;
  const u16* Kh = Kc + (size_t)bh * 131072;
  const u16* Vh = Vt + (size_t)bh * 131072;
  const int b = bh >> 4, head = bh & 15;

  __shared__ __attribute__((aligned(16))) u16 Ks[8192];
  __shared__ __attribute__((aligned(16))) u16 Vs[8192];
  __shared__ __attribute__((aligned(16))) u16 P[4][32][72];

  bf16x8 ones;
#pragma unroll
  for (int i = 0; i < 8; i++) ones[i] = (__bf16)1.0f;

  const f32x4 zero4 = {0.f, 0.f, 0.f, 0.f};

  for (int phase = 0; phase < 2; ++phase) {
    const int bt = phase ? (15 - slot) : slot;
    const int q0b = bt * 128;
    const int q0 = q0b + wid * 32;
    const int kendw = q0 + 32;
    const int nkt = bt + 1;

    bf16x8 qf[2][2];
#pragma unroll
    for (int mt = 0; mt < 2; mt++)
#pragma unroll
      for (int h = 0; h < 2; h++)
        qf[mt][h] = *(const bf16x8*)&Qh[(((q0 >> 4) + mt) * 2 + h) * 512 + lane * 8];

    f32x4 o[2][4];
    f32x4 lac[2];
#pragma unroll
    for (int mt = 0; mt < 2; mt++) {
      lac[mt] = zero4;
#pragma unroll
      for (int i = 0; i < 4; i++) o[mt][i] = zero4;
    }

    for (int kt = 0; kt < nkt; ++kt) {
      const int k0 = kt * 128;
#pragma unroll
      for (int r2 = 0; r2 < 4; r2++) {
        int idx = (r2 * 256 + tid) * 8;
        gld16(Kh + (size_t)k0 * 64 + idx, Ks + idx);
        gld16(Vh + (size_t)k0 * 64 + idx, Vs + idx);
      }
      __syncthreads();

#pragma unroll
      for (int s2 = 0; s2 < 2; ++s2) {
        const int k0s = k0 + s2 * 64;
        if (k0s < kendw) {
          bf16x8 kf[4][2], vf[4][2];
#pragma unroll
          for (int nt = 0; nt < 4; nt++)
#pragma unroll
            for (int h = 0; h < 2; h++) {
              kf[nt][h] = *(const bf16x8*)&Ks[s2 * 4096 + (nt * 2 + h) * 512 + lane * 8];
              vf[nt][h] = *(const bf16x8*)&Vs[s2 * 4096 + (nt * 2 + h) * 512 + lane * 8];
            }

          f32x4 sv[2][4];
#pragma unroll
          for (int mt = 0; mt < 2; mt++)
#pragma unroll
            for (int nt = 0; nt < 4; nt++) sv[mt][nt] = zero4;
#pragma unroll
          for (int nt = 0; nt < 4; nt++)
#pragma unroll
            for (int mt = 0; mt < 2; mt++) {
              sv[mt][nt] = MFMA(qf[mt][0], kf[nt][0], sv[mt][nt]);
              sv[mt][nt] = MFMA(qf[mt][1], kf[nt][1], sv[mt][nt]);
            }

          if (k0s + 64 > q0) {
#pragma unroll
            for (int mt = 0; mt < 2; mt++)
#pragma unroll
              for (int rr = 0; rr < 4; rr++) {
                int q = q0 + mt * 16 + g * 4 + rr;
#pragma unroll
                for (int nt = 0; nt < 4; nt++)
                  if (k0s + nt * 16 + c > q) sv[mt][nt][rr] = -1e30f;
              }
          }

#pragma unroll
          for (int mt = 0; mt < 2; mt++)
#pragma unroll
            for (int rr = 0; rr < 4; rr++) {
              union { u16x4 u; bf16x4 h; } pw;
#pragma unroll
              for (int nt = 0; nt < 4; nt++)
                pw.h[nt] = (__bf16)__builtin_amdgcn_exp2f(sv[mt][nt][rr]);
              *(u16x4*)&P[wid][mt * 16 + g * 4 + rr][4 * c] = pw.u;
            }

          asm volatile("s_waitcnt lgkmcnt(0)" ::: "memory");

#pragma unroll
          for (int mt = 0; mt < 2; mt++) {
            bf16x8 pf0 = *(const bf16x8*)&P[wid][mt * 16 + c][g * 8];
            bf16x8 pf1 = *(const bf16x8*)&P[wid][mt * 16 + c][32 + g * 8];
            lac[mt] = MFMA(pf0, ones, lac[mt]);
            lac[mt] = MFMA(pf1, ones, lac[mt]);
#pragma unroll
            for (int ot = 0; ot < 4; ot++) {
              f32x4 oo = MFMA(pf0, vf[ot][0], o[mt][ot]);
              o[mt][ot] = MFMA(pf1, vf[ot][1], oo);
            }
          }
        }
      }
      __syncthreads();
    }

    float inv[2][4];
#pragma unroll
    for (int mt = 0; mt < 2; mt++)
#pragma unroll
      for (int rr = 0; rr < 4; rr++) inv[mt][rr] = 1.0f / lac[mt][rr];
#pragma unroll
    for (int mt = 0; mt < 2; mt++)
#pragma unroll
      for (int ot = 0; ot < 4; ot++)
#pragma unroll
        for (int rr = 0; rr < 4; rr++) {
          int t = q0 + mt * 16 + g * 4 + rr;
          int hd = ot * 16 + c;
          size_t xi = ((size_t)b * 2048 + t) * 1024 + head * 64 + hd;
          float v = x[xi] + o[mt][ot][rr] * inv[mt][rr];
          x1[xi] = v;
          xb1[xi] = f2b(v);
        }
  }
}

// ---------------------------------------------------------------------------
extern "C" void kernel_launch(void* const* d_in, const int* in_sizes, int n_in,
                              void* d_out, int out_size, void* d_ws, size_t ws_size,
                              hipStream_t stream) {
  (void)in_sizes; (void)n_in; (void)out_size; (void)ws_size;
  const float* x = (const float*)d_in[0];
  const float* Wq = (const float*)d_in[1];
  const float* bq = (const float*)d_in[2];
  const float* Wk = (const float*)d_in[3];
  const float* bk = (const float*)d_in[4];
  const float* Wv = (const float*)d_in[5];
  const float* bv = (const float*)d_in[6];
  const float* W1 = (const float*)d_in[7];
  const float* b1 = (const float*)d_in[8];
  const float* W2 = (const float*)d_in[9];
  const float* b2 = (const float*)d_in[10];

  char* ws = (char*)d_ws;
  size_t off = 0;
  auto alloc = [&](size_t bytes) {
    char* p = ws + off;
    off += (bytes + 255) & ~(size_t)255;
    return p;
  };
  u16* xb    = (u16*)alloc(8192ull * 1024 * 2);   // bf16(x)
  u16* Wqkvt = (u16*)alloc(3072ull * 1024 * 2);   // [3072][1024] bf16 (Wq|Wk|Wv rows)
  u16* W1t   = (u16*)alloc(4096ull * 1024 * 2);
  u16* W2t   = (u16*)alloc(1024ull * 4096 * 2);
  u16* Qb    = (u16*)alloc(3ull * 8192 * 1024 * 2);  // Q|K|V frag-ordered, contiguous
  float* x1  = (float*)alloc(8192ull * 1024 * 4); // x + attn (fp32 residual)
  u16* hb    = (u16*)alloc(8192ull * 4096 * 2);   // gelu(x1@W1+b1)
  u16* xb1   = xb;  // xb dead after QKV gemm; reuse for bf16(x1)
  u16* Kb    = Qb + 8388608;
  u16* Vtb   = Qb + 16777216;

  const float qscale = 1.4426950408889634f / 32.0f;  // log2e / sqrt(H)

  // 1. x -> bf16
  xconv<<<dim3(8192), dim3(256), 0, stream>>>(x, xb, 8192 * 1024);
  // 2. all weight transposes in one launch
  wtrans_all<<<dim3(11264), dim3(32, 8), 0, stream>>>(
      Wq, Wk, Wv, W1, W2, Wqkvt, W1t, W2t);
  // 3. fused QKV projection (M=8192, N=3072, K=1024) -> frag-ordered Q/K/V
  //    256x256 tiles: 32 x 12 = 384 blocks
  gemm_big<4><<<dim3(384), dim3(512), 0, stream>>>(
      xb, Wqkvt, bq, bk, bv, Qb, 3072, 1024, qscale);
  // 4. attention + residual 1  (512 blocks; paired 128-row tiles)
  attn_kernel<<<dim3(512), dim3(256), 0, stream>>>(Qb, Kb, Vtb, x, x1, xb1);
  // 5. MLP1: gelu(x1 @ W1 + b1)  (M=8192, N=4096, K=1024): 32 x 16 = 512 blocks
  gemm_big<2><<<dim3(512), dim3(512), 0, stream>>>(
      xb1, W1t, b1, nullptr, nullptr, hb, 4096, 1024, 1.0f);
  // 6. MLP2 + residual 2 -> d_out (fp32) (M=8192, N=1024, K=4096): 32 x 8 = 256
  //    blocks = exactly 1 block/CU, one clean round, 64 K-tiles of pipeline.
  gemm256<3><<<dim3(256), dim3(512), 0, stream>>>(
      hb, W2t, b2, d_out, x1, 1024, 4096);
}

// Round 5
// 430.666 us; speedup vs baseline: 1.0191x; 1.0191x over previous
//
#include <hip/hip_runtime.h>
#include <cstdint>
#include <cstddef>

// Problem constants: B=4, T=2048, H=1024, NH=16, HD=64, FF=4096, M=B*T=8192
typedef unsigned short u16;
typedef __attribute__((ext_vector_type(8))) __bf16 bf16x8;
typedef __attribute__((ext_vector_type(4))) __bf16 bf16x4;
typedef __attribute__((ext_vector_type(4))) float f32x4;
typedef __attribute__((ext_vector_type(4))) u16 u16x4;

#define MFMA(a, b, c) __builtin_amdgcn_mfma_f32_16x16x32_bf16((a), (b), (c), 0, 0, 0)

__device__ __forceinline__ u16 f2b(float f) {  // native RNE cvt (1-2 ops)
  union { __bf16 h; u16 u; } v;
  v.h = (__bf16)f;
  return v.u;
}

__device__ __forceinline__ void gld16(const void* g, void* l) {
  __builtin_amdgcn_global_load_lds(
      (__attribute__((address_space(1))) void*)(void*)(g),
      (__attribute__((address_space(3))) void*)(l), 16, 0, 0);
}

// Fragment-ordered layouts (per head, 131072 u16 = 2048x64):
// Q/K: element (t, hd): chunk ((t>>4)*2 + (hd>>5)), lane ((hd>>3)&3)*16 + (t&15),
//      byte-slot hd&7. MFMA lane l reads its 16B at chunk_base + l*16B.
__device__ __forceinline__ size_t qk_off(int t, int hd) {
  return (size_t)((((t >> 4) * 2 + (hd >> 5)) * 512)
                  + ((((hd >> 3) & 3) * 16 + (t & 15)) * 8) + (hd & 7));
}
// V: keys kk-permuted within 64-groups (kk = (t&15)*4 + ((t>>4)&3)) to match the
//    P-tile LDS packing; fragment order for PV B-operand reads.
__device__ __forceinline__ size_t v_off(int t, int hd) {
  int kk = ((t & 15) << 2) | ((t >> 4) & 3);
  return (size_t)(((t >> 6) * 4096)
                  + (((hd >> 4) * 2 + (kk >> 5)) * 512)
                  + ((((kk >> 3) & 3) * 16 + (hd & 15)) * 8) + (kk & 7));
}

// ---------------------------------------------------------------------------
// elementwise fp32 -> bf16 (vectorized x4)
__global__ void xconv(const float* __restrict__ in, u16* __restrict__ out, int n) {
  int i = (blockIdx.x * blockDim.x + threadIdx.x) * 4;
  if (i >= n) return;
  float4 v = *(const float4*)(in + i);
  u16x4 o;
  o[0] = f2b(v.x); o[1] = f2b(v.y); o[2] = f2b(v.z); o[3] = f2b(v.w);
  *(u16x4*)(out + i) = o;
}

// ---------------------------------------------------------------------------
// All weight transposes in ONE launch. W [K,N] fp32 -> Wt [N,K] bf16.
__global__ void wtrans_all(const float* __restrict__ Wq, const float* __restrict__ Wk,
                           const float* __restrict__ Wv, const float* __restrict__ W1,
                           const float* __restrict__ W2, u16* __restrict__ Wqkvt,
                           u16* __restrict__ W1t, u16* __restrict__ W2t) {
  __shared__ float tile[32][33];
  int blk = blockIdx.x;
  const float* W;
  u16* Wt;
  int Kd, Nd, nx;
  if (blk < 3072) {
    int s = blk >> 10;
    blk &= 1023;
    W = (s == 0) ? Wq : (s == 1) ? Wk : Wv;
    Wt = Wqkvt + (size_t)s * 1048576;
    Kd = 1024; Nd = 1024; nx = 32;
  } else if (blk < 7168) {
    blk -= 3072; W = W1; Wt = W1t; Kd = 1024; Nd = 4096; nx = 128;
  } else {
    blk -= 7168; W = W2; Wt = W2t; Kd = 4096; Nd = 1024; nx = 32;
  }
  int n0 = (blk % nx) * 32, k0 = (blk / nx) * 32;
  int tx = threadIdx.x, ty = threadIdx.y;
#pragma unroll
  for (int i = 0; i < 4; i++)
    tile[ty + i * 8][tx] = W[(size_t)(k0 + ty + i * 8) * Nd + n0 + tx];
  __syncthreads();
#pragma unroll
  for (int i = 0; i < 4; i++)
    Wt[(size_t)(n0 + ty + i * 8) * Kd + k0 + tx] = f2b(tile[tx][ty + i * 8]);
}

// ---------------------------------------------------------------------------
// 256x256 double-buffered barrier-light GEMM ("big"). BK=64, 8 waves as
// 2M x 4N, wave tile 128x64 (acc[8][4] = 128 AGPRs). Used ONLY for linear
// epilogues (MODE 2): R4 evidence shows the MODE-4 scatter epilogue's extra
// liveness on top of 128 acc AGPRs pushes allocation past the 256/wave
// budget -> K-loop spills (QKV on this kernel: 134 us, MfmaUtil 15%), while
// MODE 2 (tiny epilogue) is the fastest MLP1 structure measured.
// Per K-tile (NO intra-tile barriers; both passes read stable buf `cur`):
//   stage A(t+1) -> read af0/bf0 -> 32 MFMA -> stage B(t+1) -> read af1/bf1
//   -> 32 MFMA -> vmcnt(0) (issued 1200-2400 cyc earlier: near-free) ->
//   s_barrier. XOR-swizzled LDS both sides. XCD mapping: xcd owns bm in
//   [4x,4x+4), bn in chunks of 4 (bijective for nbm=32, nbn%4==0).
template <int MODE>
__global__ __launch_bounds__(512, 2) void gemm_big(
    const u16* __restrict__ A, const u16* __restrict__ Bt,
    const float* __restrict__ b0, void* __restrict__ outp,
    int N, int K) {
  __shared__ __attribute__((aligned(16))) u16 As_[2][16384];
  __shared__ __attribute__((aligned(16))) u16 Bs_[2][16384];
  const int tid = threadIdx.x;
  const int wid = tid >> 6, lane = tid & 63;
  const int g = lane >> 4, r = lane & 15;

  const int xcd = blockIdx.x & 7;
  const int ii = blockIdx.x >> 3;
  const int c4 = ii >> 4, w = ii & 15;
  const int bm = xcd * 4 + (w >> 2);
  const int bn = c4 * 4 + (w & 3);

  const int wrow = (wid >> 2) * 128;  // 2 M-waves (128 rows each)
  const int wcol = (wid & 3) * 64;    // 4 N-waves (64 cols each)

  const int ko0 = ((0 * 4 + g) ^ (r & 7)) * 8;
  const int ko1 = ((1 * 4 + g) ^ (r & 7)) * 8;

  size_t aOff[4], bOff[4];
#pragma unroll
  for (int i4 = 0; i4 < 4; i4++) {
    int cc = i4 * 512 + tid, row = cc >> 3;
    int js = ((cc & 7) ^ (row & 7)) * 8;
    aOff[i4] = (size_t)(bm * 256 + row) * K + js;
    bOff[i4] = (size_t)(bn * 256 + row) * K + js;
  }

  f32x4 acc[8][4];
  const f32x4 zero4 = {0.f, 0.f, 0.f, 0.f};
#pragma unroll
  for (int i = 0; i < 8; i++)
#pragma unroll
    for (int j = 0; j < 4; j++) acc[i][j] = zero4;

  // prologue: stage tile 0 into buffer 0
#pragma unroll
  for (int i4 = 0; i4 < 4; i4++) {
    gld16(A + aOff[i4], &As_[0][(i4 * 512 + tid) * 8]);
    gld16(Bt + bOff[i4], &Bs_[0][(i4 * 512 + tid) * 8]);
  }
  asm volatile("s_waitcnt vmcnt(0)" ::: "memory");
  __builtin_amdgcn_s_barrier();

  const int KT = K >> 6;
  int cur = 0;
  for (int t = 0; t < KT; ++t) {
    const u16* as = As_[cur];
    const u16* bs = Bs_[cur];
    const int nxt = cur ^ 1;
    const bool more = (t + 1) < KT;
    const size_t k1 = (size_t)(t + 1) * 64;

    if (more) {
#pragma unroll
      for (int i4 = 0; i4 < 4; i4++)
        gld16(A + aOff[i4] + k1, &As_[nxt][(i4 * 512 + tid) * 8]);
    }

    // ---- pass 0 (k-half 0) ----
    {
      bf16x8 af[8], bf[4];
#pragma unroll
      for (int mt = 0; mt < 8; mt++)
        af[mt] = *(const bf16x8*)&as[(wrow + mt * 16 + r) * 64 + ko0];
#pragma unroll
      for (int nt = 0; nt < 4; nt++)
        bf[nt] = *(const bf16x8*)&bs[(wcol + nt * 16 + r) * 64 + ko0];
#pragma unroll
      for (int mt = 0; mt < 8; mt++)
#pragma unroll
        for (int nt = 0; nt < 4; nt++)
          acc[mt][nt] = MFMA(af[mt], bf[nt], acc[mt][nt]);
    }

    if (more) {
#pragma unroll
      for (int i4 = 0; i4 < 4; i4++)
        gld16(Bt + bOff[i4] + k1, &Bs_[nxt][(i4 * 512 + tid) * 8]);
    }

    // ---- pass 1 (k-half 1) ----
    {
      bf16x8 af[8], bf[4];
#pragma unroll
      for (int mt = 0; mt < 8; mt++)
        af[mt] = *(const bf16x8*)&as[(wrow + mt * 16 + r) * 64 + ko1];
#pragma unroll
      for (int nt = 0; nt < 4; nt++)
        bf[nt] = *(const bf16x8*)&bs[(wcol + nt * 16 + r) * 64 + ko1];
#pragma unroll
      for (int mt = 0; mt < 8; mt++)
#pragma unroll
        for (int nt = 0; nt < 4; nt++)
          acc[mt][nt] = MFMA(af[mt], bf[nt], acc[mt][nt]);
    }

    if (more) {
      asm volatile("s_waitcnt vmcnt(0)" ::: "memory");
      __builtin_amdgcn_s_barrier();
    }
    cur = nxt;
  }

  // epilogue: C[row][col], col = r (+16*nt), row = g*4 + q (+16*mt)
#pragma unroll
  for (int mt = 0; mt < 8; mt++) {
#pragma unroll
    for (int nt = 0; nt < 4; nt++) {
      int col = bn * 256 + wcol + nt * 16 + r;
      float bv = b0[col];
#pragma unroll
      for (int q = 0; q < 4; q++) {
        int row = bm * 256 + wrow + mt * 16 + g * 4 + q;
        float v = acc[mt][nt][q] + bv;
        if (MODE == 2) {
          const float c1 = -2.3025850929940457f;
          const float c2 = c1 * 0.044715f;
          float t2 = v * v;
          float z = v * (c1 + c2 * t2);
          float sg = 1.0f / (1.0f + __builtin_amdgcn_exp2f(z));
          ((u16*)outp)[(size_t)row * N + col] = f2b(v * sg);
        }
      }
    }
  }
}

// ---------------------------------------------------------------------------
// 256x128 3-buffer counted-vmcnt GEMM, barrier-light K-loop (R3 winner).
// BK=64, 8 waves as 4M x 2N (64x64/wave, acc[4][4] = 64 AGPRs -- leaves
// register headroom for the MODE-4 scatter epilogue, unlike gemm_big).
// LDS 144 KiB = 3 x (A 32K + B 16K). Per K-tile: 16x ds_read_b128 ->
// 6x gld16 stage tile t+2 -> 32 MFMA -> vmcnt(6) counted -> s_barrier.
// vmcnt(6): tile t+2's 6 loads stay in flight; t+1's (issued a full tile
// ago) guaranteed landed. XCD mapping: xcd owns bm in [4x,4x+4) x bn in
// 8-wide chunks (bijective for nbm=32, nbn%8==0).
// MODE 3: fp32 out = v + resid   MODE 4: fused QKV scatter (frag-order)
template <int MODE>
__global__ __launch_bounds__(512, 2) void gemm256(
    const u16* __restrict__ A, const u16* __restrict__ Bt,
    const float* __restrict__ b0, const float* __restrict__ b1,
    const float* __restrict__ b2, void* __restrict__ outp,
    const float* __restrict__ resid, int N, int K, float scale) {
  __shared__ __attribute__((aligned(16))) u16 As_[3][16384];
  __shared__ __attribute__((aligned(16))) u16 Bs_[3][8192];
  const int tid = threadIdx.x;
  const int wid = tid >> 6, lane = tid & 63;
  const int g = lane >> 4, r = lane & 15;

  const int xcd = blockIdx.x & 7;
  const int ii = blockIdx.x >> 3;
  const int bm = xcd * 4 + ((ii & 31) >> 3);
  const int bn = (ii >> 5) * 8 + (ii & 7);

  const int wrow = (wid >> 1) * 64;   // 4 M-waves
  const int wcol = (wid & 1) * 64;    // 2 N-waves

  const int ko0 = ((0 * 4 + g) ^ (r & 7)) * 8;
  const int ko1 = ((1 * 4 + g) ^ (r & 7)) * 8;

  size_t aOff[4], bOff[2];
#pragma unroll
  for (int i4 = 0; i4 < 4; i4++) {
    int cc = i4 * 512 + tid, row = cc >> 3;
    int js = ((cc & 7) ^ (row & 7)) * 8;
    aOff[i4] = (size_t)(bm * 256 + row) * K + js;
  }
#pragma unroll
  for (int i2 = 0; i2 < 2; i2++) {
    int cc = i2 * 512 + tid, row = cc >> 3;
    int js = ((cc & 7) ^ (row & 7)) * 8;
    bOff[i2] = (size_t)(bn * 128 + row) * K + js;
  }

  f32x4 acc[4][4];
  const f32x4 zero4 = {0.f, 0.f, 0.f, 0.f};
#pragma unroll
  for (int i = 0; i < 4; i++)
#pragma unroll
    for (int j = 0; j < 4; j++) acc[i][j] = zero4;

  // prologue: stage tiles 0 and 1; wait for tile 0 only (tile 1 in flight)
#pragma unroll
  for (int i4 = 0; i4 < 4; i4++) gld16(A + aOff[i4], &As_[0][(i4 * 512 + tid) * 8]);
#pragma unroll
  for (int i2 = 0; i2 < 2; i2++) gld16(Bt + bOff[i2], &Bs_[0][(i2 * 512 + tid) * 8]);
#pragma unroll
  for (int i4 = 0; i4 < 4; i4++) gld16(A + aOff[i4] + 64, &As_[1][(i4 * 512 + tid) * 8]);
#pragma unroll
  for (int i2 = 0; i2 < 2; i2++) gld16(Bt + bOff[i2] + 64, &Bs_[1][(i2 * 512 + tid) * 8]);
  asm volatile("s_waitcnt vmcnt(6)" ::: "memory");
  __builtin_amdgcn_s_barrier();

  const int KT = K >> 6;
  int cur = 0;
  for (int t = 0; t < KT; ++t) {
    const u16* as = As_[cur];
    const u16* bs = Bs_[cur];
    const int stg = (cur == 0) ? 2 : cur - 1;  // (t+2)%3
    const bool more = (t + 2) < KT;
    const size_t k2 = (size_t)(t + 2) * 64;

    bf16x8 af0[4], bf0[4], af1[4], bf1[4];
#pragma unroll
    for (int mt = 0; mt < 4; mt++) {
      af0[mt] = *(const bf16x8*)&as[(wrow + mt * 16 + r) * 64 + ko0];
      af1[mt] = *(const bf16x8*)&as[(wrow + mt * 16 + r) * 64 + ko1];
    }
#pragma unroll
    for (int nt = 0; nt < 4; nt++) {
      bf0[nt] = *(const bf16x8*)&bs[(wcol + nt * 16 + r) * 64 + ko0];
      bf1[nt] = *(const bf16x8*)&bs[(wcol + nt * 16 + r) * 64 + ko1];
    }

    if (more) {
#pragma unroll
      for (int i4 = 0; i4 < 4; i4++)
        gld16(A + aOff[i4] + k2, &As_[stg][(i4 * 512 + tid) * 8]);
#pragma unroll
      for (int i2 = 0; i2 < 2; i2++)
        gld16(Bt + bOff[i2] + k2, &Bs_[stg][(i2 * 512 + tid) * 8]);
    }

#pragma unroll
    for (int mt = 0; mt < 4; mt++)
#pragma unroll
      for (int nt = 0; nt < 4; nt++)
        acc[mt][nt] = MFMA(af0[mt], bf0[nt], acc[mt][nt]);
#pragma unroll
    for (int mt = 0; mt < 4; mt++)
#pragma unroll
      for (int nt = 0; nt < 4; nt++)
        acc[mt][nt] = MFMA(af1[mt], bf1[nt], acc[mt][nt]);

    if (t + 1 < KT) {
      if (more) asm volatile("s_waitcnt vmcnt(6)" ::: "memory");
      else      asm volatile("s_waitcnt vmcnt(0)" ::: "memory");
    }
    __builtin_amdgcn_s_barrier();
    cur = (cur == 2) ? 0 : cur + 1;
  }

  // epilogue: C[row][col], col = r (+16*nt), row = g*4 + q (+16*mt)
#pragma unroll
  for (int mt = 0; mt < 4; mt++) {
#pragma unroll
    for (int nt = 0; nt < 4; nt++) {
      int col = bn * 128 + wcol + nt * 16 + r;
      float bv;
      if (MODE == 4) {
        int sec = col >> 10, hcol = col & 1023;  // sec is block-uniform
        bv = (sec == 0) ? b0[hcol] : (sec == 1) ? b1[hcol] : b2[hcol];
      } else {
        bv = b0[col];
      }
#pragma unroll
      for (int q = 0; q < 4; q++) {
        int row = bm * 256 + wrow + mt * 16 + g * 4 + q;
        float v = acc[mt][nt][q] + bv;
        if (MODE == 3) {
          ((float*)outp)[(size_t)row * N + col] = v + resid[(size_t)row * N + col];
        } else if (MODE == 4) {
          int sec = col >> 10, hcol = col & 1023;
          int head = hcol >> 6, hd = hcol & 63;
          int bb = row >> 11, tt = row & 2047;
          size_t hbase = ((size_t)bb * 16 + head) * 131072;
          u16* qout = (u16*)outp;
          if (sec == 0) {
            qout[hbase + qk_off(tt, hd)] = f2b(v * scale);
          } else if (sec == 1) {
            (qout + 8388608)[hbase + qk_off(tt, hd)] = f2b(v);
          } else {
            (qout + 16777216)[hbase + v_off(tt, hd)] = f2b(v);
          }
        }
      }
    }
  }
}

// ---------------------------------------------------------------------------
// Flash attention v4 (unchanged). Causal, Q pre-scaled by log2e/32.
__global__ __launch_bounds__(256) void attn_kernel(
    const u16* __restrict__ Q, const u16* __restrict__ Kc,
    const u16* __restrict__ Vt, const float* __restrict__ x,
    float* __restrict__ x1, u16* __restrict__ xb1) {
  const int bh = blockIdx.x & 63;
  const int slot = blockIdx.x >> 6;
  const int tid = threadIdx.x;
  const int wid = tid >> 6, lane = tid & 63;
  const int g = lane >> 4, c = lane & 15;
  const u16* Qh = Q + (size_t)bh * 131072;
  const u16* Kh = Kc + (size_t)bh * 131072;
  const u16* Vh = Vt + (size_t)bh * 131072;
  const int b = bh >> 4, head = bh & 15;

  __shared__ __attribute__((aligned(16))) u16 Ks[8192];
  __shared__ __attribute__((aligned(16))) u16 Vs[8192];
  __shared__ __attribute__((aligned(16))) u16 P[4][32][72];

  bf16x8 ones;
#pragma unroll
  for (int i = 0; i < 8; i++) ones[i] = (__bf16)1.0f;

  const f32x4 zero4 = {0.f, 0.f, 0.f, 0.f};

  for (int phase = 0; phase < 2; ++phase) {
    const int bt = phase ? (15 - slot) : slot;
    const int q0b = bt * 128;
    const int q0 = q0b + wid * 32;
    const int kendw = q0 + 32;
    const int nkt = bt + 1;

    bf16x8 qf[2][2];
#pragma unroll
    for (int mt = 0; mt < 2; mt++)
#pragma unroll
      for (int h = 0; h < 2; h++)
        qf[mt][h] = *(const bf16x8*)&Qh[(((q0 >> 4) + mt) * 2 + h) * 512 + lane * 8];

    f32x4 o[2][4];
    f32x4 lac[2];
#pragma unroll
    for (int mt = 0; mt < 2; mt++) {
      lac[mt] = zero4;
#pragma unroll
      for (int i = 0; i < 4; i++) o[mt][i] = zero4;
    }

    for (int kt = 0; kt < nkt; ++kt) {
      const int k0 = kt * 128;
#pragma unroll
      for (int r2 = 0; r2 < 4; r2++) {
        int idx = (r2 * 256 + tid) * 8;
        gld16(Kh + (size_t)k0 * 64 + idx, Ks + idx);
        gld16(Vh + (size_t)k0 * 64 + idx, Vs + idx);
      }
      __syncthreads();

#pragma unroll
      for (int s2 = 0; s2 < 2; ++s2) {
        const int k0s = k0 + s2 * 64;
        if (k0s < kendw) {
          bf16x8 kf[4][2], vf[4][2];
#pragma unroll
          for (int nt = 0; nt < 4; nt++)
#pragma unroll
            for (int h = 0; h < 2; h++) {
              kf[nt][h] = *(const bf16x8*)&Ks[s2 * 4096 + (nt * 2 + h) * 512 + lane * 8];
              vf[nt][h] = *(const bf16x8*)&Vs[s2 * 4096 + (nt * 2 + h) * 512 + lane * 8];
            }

          f32x4 sv[2][4];
#pragma unroll
          for (int mt = 0; mt < 2; mt++)
#pragma unroll
            for (int nt = 0; nt < 4; nt++) sv[mt][nt] = zero4;
#pragma unroll
          for (int nt = 0; nt < 4; nt++)
#pragma unroll
            for (int mt = 0; mt < 2; mt++) {
              sv[mt][nt] = MFMA(qf[mt][0], kf[nt][0], sv[mt][nt]);
              sv[mt][nt] = MFMA(qf[mt][1], kf[nt][1], sv[mt][nt]);
            }

          if (k0s + 64 > q0) {
#pragma unroll
            for (int mt = 0; mt < 2; mt++)
#pragma unroll
              for (int rr = 0; rr < 4; rr++) {
                int q = q0 + mt * 16 + g * 4 + rr;
#pragma unroll
                for (int nt = 0; nt < 4; nt++)
                  if (k0s + nt * 16 + c > q) sv[mt][nt][rr] = -1e30f;
              }
          }

#pragma unroll
          for (int mt = 0; mt < 2; mt++)
#pragma unroll
            for (int rr = 0; rr < 4; rr++) {
              union { u16x4 u; bf16x4 h; } pw;
#pragma unroll
              for (int nt = 0; nt < 4; nt++)
                pw.h[nt] = (__bf16)__builtin_amdgcn_exp2f(sv[mt][nt][rr]);
              *(u16x4*)&P[wid][mt * 16 + g * 4 + rr][4 * c] = pw.u;
            }

          asm volatile("s_waitcnt lgkmcnt(0)" ::: "memory");

#pragma unroll
          for (int mt = 0; mt < 2; mt++) {
            bf16x8 pf0 = *(const bf16x8*)&P[wid][mt * 16 + c][g * 8];
            bf16x8 pf1 = *(const bf16x8*)&P[wid][mt * 16 + c][32 + g * 8];
            lac[mt] = MFMA(pf0, ones, lac[mt]);
            lac[mt] = MFMA(pf1, ones, lac[mt]);
#pragma unroll
            for (int ot = 0; ot < 4; ot++) {
              f32x4 oo = MFMA(pf0, vf[ot][0], o[mt][ot]);
              o[mt][ot] = MFMA(pf1, vf[ot][1], oo);
            }
          }
        }
      }
      __syncthreads();
    }

    float inv[2][4];
#pragma unroll
    for (int mt = 0; mt < 2; mt++)
#pragma unroll
      for (int rr = 0; rr < 4; rr++) inv[mt][rr] = 1.0f / lac[mt][rr];
#pragma unroll
    for (int mt = 0; mt < 2; mt++)
#pragma unroll
      for (int ot = 0; ot < 4; ot++)
#pragma unroll
        for (int rr = 0; rr < 4; rr++) {
          int t = q0 + mt * 16 + g * 4 + rr;
          int hd = ot * 16 + c;
          size_t xi = ((size_t)b * 2048 + t) * 1024 + head * 64 + hd;
          float v = x[xi] + o[mt][ot][rr] * inv[mt][rr];
          x1[xi] = v;
          xb1[xi] = f2b(v);
        }
  }
}

// ---------------------------------------------------------------------------
extern "C" void kernel_launch(void* const* d_in, const int* in_sizes, int n_in,
                              void* d_out, int out_size, void* d_ws, size_t ws_size,
                              hipStream_t stream) {
  (void)in_sizes; (void)n_in; (void)out_size; (void)ws_size;
  const float* x = (const float*)d_in[0];
  const float* Wq = (const float*)d_in[1];
  const float* bq = (const float*)d_in[2];
  const float* Wk = (const float*)d_in[3];
  const float* bk = (const float*)d_in[4];
  const float* Wv = (const float*)d_in[5];
  const float* bv = (const float*)d_in[6];
  const float* W1 = (const float*)d_in[7];
  const float* b1 = (const float*)d_in[8];
  const float* W2 = (const float*)d_in[9];
  const float* b2 = (const float*)d_in[10];

  char* ws = (char*)d_ws;
  size_t off = 0;
  auto alloc = [&](size_t bytes) {
    char* p = ws + off;
    off += (bytes + 255) & ~(size_t)255;
    return p;
  };
  u16* xb    = (u16*)alloc(8192ull * 1024 * 2);   // bf16(x)
  u16* Wqkvt = (u16*)alloc(3072ull * 1024 * 2);   // [3072][1024] bf16 (Wq|Wk|Wv rows)
  u16* W1t   = (u16*)alloc(4096ull * 1024 * 2);
  u16* W2t   = (u16*)alloc(1024ull * 4096 * 2);
  u16* Qb    = (u16*)alloc(3ull * 8192 * 1024 * 2);  // Q|K|V frag-ordered, contiguous
  float* x1  = (float*)alloc(8192ull * 1024 * 4); // x + attn (fp32 residual)
  u16* hb    = (u16*)alloc(8192ull * 4096 * 2);   // gelu(x1@W1+b1)
  u16* xb1   = xb;  // xb dead after QKV gemm; reuse for bf16(x1)
  u16* Kb    = Qb + 8388608;
  u16* Vtb   = Qb + 16777216;

  const float qscale = 1.4426950408889634f / 32.0f;  // log2e / sqrt(H)

  // 1. x -> bf16
  xconv<<<dim3(8192), dim3(256), 0, stream>>>(x, xb, 8192 * 1024);
  // 2. all weight transposes in one launch
  wtrans_all<<<dim3(11264), dim3(32, 8), 0, stream>>>(
      Wq, Wk, Wv, W1, W2, Wqkvt, W1t, W2t);
  // 3. fused QKV projection (M=8192, N=3072, K=1024) -> frag-ordered Q/K/V
  //    R3-proven 256x128 3-buffer (acc=64: scatter epilogue fits registers)
  gemm256<4><<<dim3(768), dim3(512), 0, stream>>>(
      xb, Wqkvt, bq, bk, bv, Qb, nullptr, 3072, 1024, qscale);
  // 4. attention + residual 1  (512 blocks; paired 128-row tiles)
  attn_kernel<<<dim3(512), dim3(256), 0, stream>>>(Qb, Kb, Vtb, x, x1, xb1);
  // 5. MLP1: gelu(x1 @ W1 + b1): 256x256 double-buffered (R4 winner for
  //    linear epilogues), 32 x 16 = 512 blocks
  gemm_big<2><<<dim3(512), dim3(512), 0, stream>>>(
      xb1, W1t, b1, hb, 4096, 1024);
  // 6. MLP2 + residual 2 -> d_out (fp32) (M=8192, N=1024, K=4096): 32 x 8 = 256
  //    blocks = exactly 1 block/CU, one clean round, 64 K-tiles of pipeline.
  gemm256<3><<<dim3(256), dim3(512), 0, stream>>>(
      hb, W2t, b2, nullptr, nullptr, d_out, x1, 1024, 4096, 1.0f);
}

// Round 7
// 425.528 us; speedup vs baseline: 1.0314x; 1.0121x over previous
//
#include <hip/hip_runtime.h>
#include <cstdint>
#include <cstddef>

// Problem constants: B=4, T=2048, H=1024, NH=16, HD=64, FF=4096, M=B*T=8192
typedef unsigned short u16;
typedef __attribute__((ext_vector_type(8))) __bf16 bf16x8;
typedef __attribute__((ext_vector_type(4))) __bf16 bf16x4;
typedef __attribute__((ext_vector_type(4))) float f32x4;
typedef __attribute__((ext_vector_type(4))) u16 u16x4;

#define MFMA(a, b, c) __builtin_amdgcn_mfma_f32_16x16x32_bf16((a), (b), (c), 0, 0, 0)

__device__ __forceinline__ u16 f2b(float f) {  // native RNE cvt (1-2 ops)
  union { __bf16 h; u16 u; } v;
  v.h = (__bf16)f;
  return v.u;
}

__device__ __forceinline__ void gld16(const void* g, void* l) {
  __builtin_amdgcn_global_load_lds(
      (__attribute__((address_space(1))) void*)(void*)(g),
      (__attribute__((address_space(3))) void*)(l), 16, 0, 0);
}

// Fragment-ordered layouts (per head, 131072 u16 = 2048x64):
__device__ __forceinline__ size_t qk_off(int t, int hd) {
  return (size_t)((((t >> 4) * 2 + (hd >> 5)) * 512)
                  + ((((hd >> 3) & 3) * 16 + (t & 15)) * 8) + (hd & 7));
}
__device__ __forceinline__ size_t v_off(int t, int hd) {
  int kk = ((t & 15) << 2) | ((t >> 4) & 3);
  return (size_t)(((t >> 6) * 4096)
                  + (((hd >> 4) * 2 + (kk >> 5)) * 512)
                  + ((((kk >> 3) & 3) * 16 + (hd & 15)) * 8) + (kk & 7));
}

// ---------------------------------------------------------------------------
// elementwise fp32 -> bf16 (vectorized x4)
__global__ void xconv(const float* __restrict__ in, u16* __restrict__ out, int n) {
  int i = (blockIdx.x * blockDim.x + threadIdx.x) * 4;
  if (i >= n) return;
  float4 v = *(const float4*)(in + i);
  u16x4 o;
  o[0] = f2b(v.x); o[1] = f2b(v.y); o[2] = f2b(v.z); o[3] = f2b(v.w);
  *(u16x4*)(out + i) = o;
}

// ---------------------------------------------------------------------------
// All weight transposes in ONE launch. W [K,N] fp32 -> Wt [N,K] bf16.
__global__ void wtrans_all(const float* __restrict__ Wq, const float* __restrict__ Wk,
                           const float* __restrict__ Wv, const float* __restrict__ W1,
                           const float* __restrict__ W2, u16* __restrict__ Wqkvt,
                           u16* __restrict__ W1t, u16* __restrict__ W2t) {
  __shared__ float tile[32][33];
  int blk = blockIdx.x;
  const float* W;
  u16* Wt;
  int Kd, Nd, nx;
  if (blk < 3072) {
    int s = blk >> 10;
    blk &= 1023;
    W = (s == 0) ? Wq : (s == 1) ? Wk : Wv;
    Wt = Wqkvt + (size_t)s * 1048576;
    Kd = 1024; Nd = 1024; nx = 32;
  } else if (blk < 7168) {
    blk -= 3072; W = W1; Wt = W1t; Kd = 1024; Nd = 4096; nx = 128;
  } else {
    blk -= 7168; W = W2; Wt = W2t; Kd = 4096; Nd = 1024; nx = 32;
  }
  int n0 = (blk % nx) * 32, k0 = (blk / nx) * 32;
  int tx = threadIdx.x, ty = threadIdx.y;
#pragma unroll
  for (int i = 0; i < 4; i++)
    tile[ty + i * 8][tx] = W[(size_t)(k0 + ty + i * 8) * Nd + n0 + tx];
  __syncthreads();
#pragma unroll
  for (int i = 0; i < 4; i++)
    Wt[(size_t)(n0 + ty + i * 8) * Kd + k0 + tx] = f2b(tile[tx][ty + i * 8]);
}

// ---------------------------------------------------------------------------
// 256x256 8-phase COUNTED-vmcnt GEMM ("8p"). BK=64, 8 waves; quadrant
// (mh,nh) selects the OPERAND HALF: A-half mh (128 rows) is read by ALL
// waves during the two mh-phases (wave's rows = mh*128 + (wid>>2)*64 + ...),
// likewise B-half nh. Phase order gray-coded (0,0),(0,1),(1,1),(1,0) so
// A0 frees after ph1, B1 after ph2. Staging units (16KB = 2 gld16/thread):
//   ph0: A1(t+1) -> buf[t+1]   (region freed at end of tile t-1)
//   ph1: B0(t+1) -> buf[t+1]   (freed at end of tile t-1)
//   ph2: A0(t+2) -> buf[t]     (this tile's A0, freed at ph1 barrier)
//   ph3: B1(t+2) -> buf[t]     (this tile's B1, freed at ph2 barrier)
// End-of-tile wait = vmcnt(4): only the 2 newest units (A0/B1 of t+2,
// issued this tile) may stay in flight -- everything tile t+1 needs landed
// >=2 phases after issue (2400+ cyc cover). NEVER drains (T4). Each phase:
// {ds_read 4-12 b128 | 2 gld16} -> barrier -> lgkmcnt(0)+sched_barrier ->
// setprio(1) 16 MFMA setprio(0) -> barrier (T3+T5). XOR-swizzled LDS.
// XCD map: xcd owns bm in [4x,4x+4), bn chunks of 4 (nbm=32, nbn%4==0).
// MODE 2: bf16 out = gelu(v).
template <int MODE>
__global__ __launch_bounds__(512, 2) void gemm8p(
    const u16* __restrict__ A, const u16* __restrict__ Bt,
    const float* __restrict__ b0, void* __restrict__ outp,
    int N, int K) {
  __shared__ __attribute__((aligned(16))) u16 As_[2][16384];
  __shared__ __attribute__((aligned(16))) u16 Bs_[2][16384];
  const int tid = threadIdx.x;
  const int wid = tid >> 6, lane = tid & 63;
  const int g = lane >> 4, r = lane & 15;

  const int xcd = blockIdx.x & 7;
  const int ii = blockIdx.x >> 3;
  const int c4 = ii >> 4, w = ii & 15;
  const int bm = xcd * 4 + (w >> 2);
  const int bn = c4 * 4 + (w & 3);

  const int mrow = (wid >> 2) * 64;   // wave's 64-row band within each A-half
  const int ncol = (wid & 3) * 32;    // wave's 32-col band within each B-half

  const int ko0 = ((0 * 4 + g) ^ (r & 7)) * 8;
  const int ko1 = ((1 * 4 + g) ^ (r & 7)) * 8;

  // staging source offsets; unit i4: rows [i4*64, i4*64+64). i4 0,1 = half 0.
  size_t aOff[4], bOff[4];
#pragma unroll
  for (int i4 = 0; i4 < 4; i4++) {
    int cc = i4 * 512 + tid, row = cc >> 3;
    int js = ((cc & 7) ^ (row & 7)) * 8;
    aOff[i4] = (size_t)(bm * 256 + row) * K + js;
    bOff[i4] = (size_t)(bn * 256 + row) * K + js;
  }

  f32x4 acc[8][4];
  const f32x4 zero4 = {0.f, 0.f, 0.f, 0.f};
#pragma unroll
  for (int i = 0; i < 8; i++)
#pragma unroll
    for (int j = 0; j < 4; j++) acc[i][j] = zero4;

  // prologue: all 4 units of tile 0 -> buf0; A0(1), B1(1) -> buf1
#pragma unroll
  for (int i4 = 0; i4 < 4; i4++) {
    gld16(A + aOff[i4], &As_[0][(i4 * 512 + tid) * 8]);
    gld16(Bt + bOff[i4], &Bs_[0][(i4 * 512 + tid) * 8]);
  }
  gld16(A + aOff[0] + 64, &As_[1][(0 * 512 + tid) * 8]);
  gld16(A + aOff[1] + 64, &As_[1][(1 * 512 + tid) * 8]);
  gld16(Bt + bOff[2] + 64, &Bs_[1][(2 * 512 + tid) * 8]);
  gld16(Bt + bOff[3] + 64, &Bs_[1][(3 * 512 + tid) * 8]);
  asm volatile("s_waitcnt vmcnt(4)" ::: "memory");  // tile 0 landed
  __builtin_amdgcn_s_barrier();

  const int KT = K >> 6;
  for (int t = 0; t < KT; ++t) {
    const int p = t & 1, pn = p ^ 1;
    const u16* as = As_[p];
    const u16* bs = Bs_[p];
    const bool m1 = (t + 1) < KT, m2 = (t + 2) < KT;
    const size_t k1 = (size_t)(t + 1) * 64, k2 = (size_t)(t + 2) * 64;
    bf16x8 af[4][2], bf[2][2];

    // ---- phase 0: quadrant (mh0, nh0); stage A1(t+1) ----
#pragma unroll
    for (int mt = 0; mt < 4; mt++) {
      int rw = mrow + mt * 16 + r;
      af[mt][0] = *(const bf16x8*)&as[rw * 64 + ko0];
      af[mt][1] = *(const bf16x8*)&as[rw * 64 + ko1];
    }
#pragma unroll
    for (int nt = 0; nt < 2; nt++) {
      int rw = ncol + nt * 16 + r;
      bf[nt][0] = *(const bf16x8*)&bs[rw * 64 + ko0];
      bf[nt][1] = *(const bf16x8*)&bs[rw * 64 + ko1];
    }
    if (m1) {
      gld16(A + aOff[2] + k1, &As_[pn][(1024 + tid) * 8]);
      gld16(A + aOff[3] + k1, &As_[pn][(1536 + tid) * 8]);
    }
    __builtin_amdgcn_s_barrier();
    asm volatile("s_waitcnt lgkmcnt(0)" ::: "memory");
    __builtin_amdgcn_sched_barrier(0);
    __builtin_amdgcn_s_setprio(1);
#pragma unroll
    for (int mt = 0; mt < 4; mt++)
#pragma unroll
      for (int nt = 0; nt < 2; nt++)
        acc[mt][nt] = MFMA(af[mt][1], bf[nt][1], MFMA(af[mt][0], bf[nt][0], acc[mt][nt]));
    __builtin_amdgcn_s_setprio(0);
    __builtin_amdgcn_s_barrier();

    // ---- phase 1: (mh0, nh1); stage B0(t+1) ----
#pragma unroll
    for (int nt = 0; nt < 2; nt++) {
      int rw = 128 + ncol + nt * 16 + r;
      bf[nt][0] = *(const bf16x8*)&bs[rw * 64 + ko0];
      bf[nt][1] = *(const bf16x8*)&bs[rw * 64 + ko1];
    }
    if (m1) {
      gld16(Bt + bOff[0] + k1, &Bs_[pn][(tid) * 8]);
      gld16(Bt + bOff[1] + k1, &Bs_[pn][(512 + tid) * 8]);
    }
    __builtin_amdgcn_s_barrier();
    asm volatile("s_waitcnt lgkmcnt(0)" ::: "memory");
    __builtin_amdgcn_sched_barrier(0);
    __builtin_amdgcn_s_setprio(1);
#pragma unroll
    for (int mt = 0; mt < 4; mt++)
#pragma unroll
      for (int nt = 0; nt < 2; nt++)
        acc[mt][2 + nt] = MFMA(af[mt][1], bf[nt][1], MFMA(af[mt][0], bf[nt][0], acc[mt][2 + nt]));
    __builtin_amdgcn_s_setprio(0);
    __builtin_amdgcn_s_barrier();   // A0 region of buf[p] now free

    // ---- phase 2: (mh1, nh1); stage A0(t+2) into buf[p] ----
#pragma unroll
    for (int mt = 0; mt < 4; mt++) {
      int rw = 128 + mrow + mt * 16 + r;
      af[mt][0] = *(const bf16x8*)&as[rw * 64 + ko0];
      af[mt][1] = *(const bf16x8*)&as[rw * 64 + ko1];
    }
    if (m2) {
      gld16(A + aOff[0] + k2, &As_[p][(tid) * 8]);
      gld16(A + aOff[1] + k2, &As_[p][(512 + tid) * 8]);
    }
    __builtin_amdgcn_s_barrier();
    asm volatile("s_waitcnt lgkmcnt(0)" ::: "memory");
    __builtin_amdgcn_sched_barrier(0);
    __builtin_amdgcn_s_setprio(1);
#pragma unroll
    for (int mt = 0; mt < 4; mt++)
#pragma unroll
      for (int nt = 0; nt < 2; nt++)
        acc[4 + mt][2 + nt] = MFMA(af[mt][1], bf[nt][1], MFMA(af[mt][0], bf[nt][0], acc[4 + mt][2 + nt]));
    __builtin_amdgcn_s_setprio(0);
    __builtin_amdgcn_s_barrier();   // B1 region of buf[p] now free

    // ---- phase 3: (mh1, nh0); stage B1(t+2) into buf[p] ----
#pragma unroll
    for (int nt = 0; nt < 2; nt++) {
      int rw = ncol + nt * 16 + r;
      bf[nt][0] = *(const bf16x8*)&bs[rw * 64 + ko0];
      bf[nt][1] = *(const bf16x8*)&bs[rw * 64 + ko1];
    }
    if (m2) {
      gld16(Bt + bOff[2] + k2, &Bs_[p][(1024 + tid) * 8]);
      gld16(Bt + bOff[3] + k2, &Bs_[p][(1536 + tid) * 8]);
    }
    __builtin_amdgcn_s_barrier();
    asm volatile("s_waitcnt lgkmcnt(0)" ::: "memory");
    __builtin_amdgcn_sched_barrier(0);
    __builtin_amdgcn_s_setprio(1);
#pragma unroll
    for (int mt = 0; mt < 4; mt++)
#pragma unroll
      for (int nt = 0; nt < 2; nt++)
        acc[4 + mt][nt] = MFMA(af[mt][1], bf[nt][1], MFMA(af[mt][0], bf[nt][0], acc[4 + mt][nt]));
    __builtin_amdgcn_s_setprio(0);
    // counted wait: only A0(t+2)/B1(t+2) (4 loads, issued this tile) may
    // stay in flight; all of tile t+1 guaranteed landed.
    if (m2) asm volatile("s_waitcnt vmcnt(4)" ::: "memory");
    else    asm volatile("s_waitcnt vmcnt(0)" ::: "memory");
    __builtin_amdgcn_s_barrier();
  }

  // epilogue: row = bm*256 + mh*128 + mrow + mt*16 + g*4 + q,
  //           col = bn*256 + nh*128 + ncol + nt*16 + r
#pragma unroll
  for (int am = 0; am < 8; am++) {
#pragma unroll
    for (int an = 0; an < 4; an++) {
      int col = bn * 256 + (an >> 1) * 128 + ncol + (an & 1) * 16 + r;
      float bv = b0[col];
#pragma unroll
      for (int q = 0; q < 4; q++) {
        int row = bm * 256 + (am >> 2) * 128 + mrow + (am & 3) * 16 + g * 4 + q;
        float v = acc[am][an][q] + bv;
        if (MODE == 2) {
          const float c1 = -2.3025850929940457f;
          const float c2 = c1 * 0.044715f;
          float t2 = v * v;
          float z = v * (c1 + c2 * t2);
          float sg = 1.0f / (1.0f + __builtin_amdgcn_exp2f(z));
          ((u16*)outp)[(size_t)row * N + col] = f2b(v * sg);
        }
      }
    }
  }
}

// ---------------------------------------------------------------------------
// 256x128 3-buffer counted-vmcnt GEMM, barrier-light K-loop (R3 winner).
// acc[4][4] = 64 AGPRs: register headroom for the MODE-4 scatter epilogue.
// MODE 3: fp32 out = v + resid   MODE 4: fused QKV scatter (frag-order)
template <int MODE>
__global__ __launch_bounds__(512, 2) void gemm256(
    const u16* __restrict__ A, const u16* __restrict__ Bt,
    const float* __restrict__ b0, const float* __restrict__ b1,
    const float* __restrict__ b2, void* __restrict__ outp,
    const float* __restrict__ resid, int N, int K, float scale) {
  __shared__ __attribute__((aligned(16))) u16 As_[3][16384];
  __shared__ __attribute__((aligned(16))) u16 Bs_[3][8192];
  const int tid = threadIdx.x;
  const int wid = tid >> 6, lane = tid & 63;
  const int g = lane >> 4, r = lane & 15;

  const int xcd = blockIdx.x & 7;
  const int ii = blockIdx.x >> 3;
  const int bm = xcd * 4 + ((ii & 31) >> 3);
  const int bn = (ii >> 5) * 8 + (ii & 7);

  const int wrow = (wid >> 1) * 64;   // 4 M-waves
  const int wcol = (wid & 1) * 64;    // 2 N-waves

  const int ko0 = ((0 * 4 + g) ^ (r & 7)) * 8;
  const int ko1 = ((1 * 4 + g) ^ (r & 7)) * 8;

  size_t aOff[4], bOff[2];
#pragma unroll
  for (int i4 = 0; i4 < 4; i4++) {
    int cc = i4 * 512 + tid, row = cc >> 3;
    int js = ((cc & 7) ^ (row & 7)) * 8;
    aOff[i4] = (size_t)(bm * 256 + row) * K + js;
  }
#pragma unroll
  for (int i2 = 0; i2 < 2; i2++) {
    int cc = i2 * 512 + tid, row = cc >> 3;
    int js = ((cc & 7) ^ (row & 7)) * 8;
    bOff[i2] = (size_t)(bn * 128 + row) * K + js;
  }

  f32x4 acc[4][4];
  const f32x4 zero4 = {0.f, 0.f, 0.f, 0.f};
#pragma unroll
  for (int i = 0; i < 4; i++)
#pragma unroll
    for (int j = 0; j < 4; j++) acc[i][j] = zero4;

  // prologue: stage tiles 0 and 1; wait for tile 0 only (tile 1 in flight)
#pragma unroll
  for (int i4 = 0; i4 < 4; i4++) gld16(A + aOff[i4], &As_[0][(i4 * 512 + tid) * 8]);
#pragma unroll
  for (int i2 = 0; i2 < 2; i2++) gld16(Bt + bOff[i2], &Bs_[0][(i2 * 512 + tid) * 8]);
#pragma unroll
  for (int i4 = 0; i4 < 4; i4++) gld16(A + aOff[i4] + 64, &As_[1][(i4 * 512 + tid) * 8]);
#pragma unroll
  for (int i2 = 0; i2 < 2; i2++) gld16(Bt + bOff[i2] + 64, &Bs_[1][(i2 * 512 + tid) * 8]);
  asm volatile("s_waitcnt vmcnt(6)" ::: "memory");
  __builtin_amdgcn_s_barrier();

  const int KT = K >> 6;
  int cur = 0;
  for (int t = 0; t < KT; ++t) {
    const u16* as = As_[cur];
    const u16* bs = Bs_[cur];
    const int stg = (cur == 0) ? 2 : cur - 1;  // (t+2)%3
    const bool more = (t + 2) < KT;
    const size_t k2 = (size_t)(t + 2) * 64;

    bf16x8 af0[4], bf0[4], af1[4], bf1[4];
#pragma unroll
    for (int mt = 0; mt < 4; mt++) {
      af0[mt] = *(const bf16x8*)&as[(wrow + mt * 16 + r) * 64 + ko0];
      af1[mt] = *(const bf16x8*)&as[(wrow + mt * 16 + r) * 64 + ko1];
    }
#pragma unroll
    for (int nt = 0; nt < 4; nt++) {
      bf0[nt] = *(const bf16x8*)&bs[(wcol + nt * 16 + r) * 64 + ko0];
      bf1[nt] = *(const bf16x8*)&bs[(wcol + nt * 16 + r) * 64 + ko1];
    }

    if (more) {
#pragma unroll
      for (int i4 = 0; i4 < 4; i4++)
        gld16(A + aOff[i4] + k2, &As_[stg][(i4 * 512 + tid) * 8]);
#pragma unroll
      for (int i2 = 0; i2 < 2; i2++)
        gld16(Bt + bOff[i2] + k2, &Bs_[stg][(i2 * 512 + tid) * 8]);
    }

#pragma unroll
    for (int mt = 0; mt < 4; mt++)
#pragma unroll
      for (int nt = 0; nt < 4; nt++)
        acc[mt][nt] = MFMA(af0[mt], bf0[nt], acc[mt][nt]);
#pragma unroll
    for (int mt = 0; mt < 4; mt++)
#pragma unroll
      for (int nt = 0; nt < 4; nt++)
        acc[mt][nt] = MFMA(af1[mt], bf1[nt], acc[mt][nt]);

    if (t + 1 < KT) {
      if (more) asm volatile("s_waitcnt vmcnt(6)" ::: "memory");
      else      asm volatile("s_waitcnt vmcnt(0)" ::: "memory");
    }
    __builtin_amdgcn_s_barrier();
    cur = (cur == 2) ? 0 : cur + 1;
  }

  // epilogue: C[row][col], col = r (+16*nt), row = g*4 + q (+16*mt)
#pragma unroll
  for (int mt = 0; mt < 4; mt++) {
#pragma unroll
    for (int nt = 0; nt < 4; nt++) {
      int col = bn * 128 + wcol + nt * 16 + r;
      float bv;
      if (MODE == 4) {
        int sec = col >> 10, hcol = col & 1023;  // sec is block-uniform
        bv = (sec == 0) ? b0[hcol] : (sec == 1) ? b1[hcol] : b2[hcol];
      } else {
        bv = b0[col];
      }
#pragma unroll
      for (int q = 0; q < 4; q++) {
        int row = bm * 256 + wrow + mt * 16 + g * 4 + q;
        float v = acc[mt][nt][q] + bv;
        if (MODE == 3) {
          ((float*)outp)[(size_t)row * N + col] = v + resid[(size_t)row * N + col];
        } else if (MODE == 4) {
          int sec = col >> 10, hcol = col & 1023;
          int head = hcol >> 6, hd = hcol & 63;
          int bb = row >> 11, tt = row & 2047;
          size_t hbase = ((size_t)bb * 16 + head) * 131072;
          u16* qout = (u16*)outp;
          if (sec == 0) {
            qout[hbase + qk_off(tt, hd)] = f2b(v * scale);
          } else if (sec == 1) {
            (qout + 8388608)[hbase + qk_off(tt, hd)] = f2b(v);
          } else {
            (qout + 16777216)[hbase + v_off(tt, hd)] = f2b(v);
          }
        }
      }
    }
  }
}

// ---------------------------------------------------------------------------
// Flash attention v4 (unchanged). Causal, Q pre-scaled by log2e/32.
__global__ __launch_bounds__(256) void attn_kernel(
    const u16* __restrict__ Q, const u16* __restrict__ Kc,
    const u16* __restrict__ Vt, const float* __restrict__ x,
    float* __restrict__ x1, u16* __restrict__ xb1) {
  const int bh = blockIdx.x & 63;
  const int slot = blockIdx.x >> 6;
  const int tid = threadIdx.x;
  const int wid = tid >> 6, lane = tid & 63;
  const int g = lane >> 4, c = lane & 15;
  const u16* Qh = Q + (size_t)bh * 131072;
  const u16* Kh = Kc + (size_t)bh * 131072;
  const u16* Vh = Vt + (size_t)bh * 131072;
  const int b = bh >> 4, head = bh & 15;

  __shared__ __attribute__((aligned(16))) u16 Ks[8192];
  __shared__ __attribute__((aligned(16))) u16 Vs[8192];
  __shared__ __attribute__((aligned(16))) u16 P[4][32][72];

  bf16x8 ones;
#pragma unroll
  for (int i = 0; i < 8; i++) ones[i] = (__bf16)1.0f;

  const f32x4 zero4 = {0.f, 0.f, 0.f, 0.f};

  for (int phase = 0; phase < 2; ++phase) {
    const int bt = phase ? (15 - slot) : slot;
    const int q0b = bt * 128;
    const int q0 = q0b + wid * 32;
    const int kendw = q0 + 32;
    const int nkt = bt + 1;

    bf16x8 qf[2][2];
#pragma unroll
    for (int mt = 0; mt < 2; mt++)
#pragma unroll
      for (int h = 0; h < 2; h++)
        qf[mt][h] = *(const bf16x8*)&Qh[(((q0 >> 4) + mt) * 2 + h) * 512 + lane * 8];

    f32x4 o[2][4];
    f32x4 lac[2];
#pragma unroll
    for (int mt = 0; mt < 2; mt++) {
      lac[mt] = zero4;
#pragma unroll
      for (int i = 0; i < 4; i++) o[mt][i] = zero4;
    }

    for (int kt = 0; kt < nkt; ++kt) {
      const int k0 = kt * 128;
#pragma unroll
      for (int r2 = 0; r2 < 4; r2++) {
        int idx = (r2 * 256 + tid) * 8;
        gld16(Kh + (size_t)k0 * 64 + idx, Ks + idx);
        gld16(Vh + (size_t)k0 * 64 + idx, Vs + idx);
      }
      __syncthreads();

#pragma unroll
      for (int s2 = 0; s2 < 2; ++s2) {
        const int k0s = k0 + s2 * 64;
        if (k0s < kendw) {
          bf16x8 kf[4][2], vf[4][2];
#pragma unroll
          for (int nt = 0; nt < 4; nt++)
#pragma unroll
            for (int h = 0; h < 2; h++) {
              kf[nt][h] = *(const bf16x8*)&Ks[s2 * 4096 + (nt * 2 + h) * 512 + lane * 8];
              vf[nt][h] = *(const bf16x8*)&Vs[s2 * 4096 + (nt * 2 + h) * 512 + lane * 8];
            }

          f32x4 sv[2][4];
#pragma unroll
          for (int mt = 0; mt < 2; mt++)
#pragma unroll
            for (int nt = 0; nt < 4; nt++) sv[mt][nt] = zero4;
#pragma unroll
          for (int nt = 0; nt < 4; nt++)
#pragma unroll
            for (int mt = 0; mt < 2; mt++) {
              sv[mt][nt] = MFMA(qf[mt][0], kf[nt][0], sv[mt][nt]);
              sv[mt][nt] = MFMA(qf[mt][1], kf[nt][1], sv[mt][nt]);
            }

          if (k0s + 64 > q0) {
#pragma unroll
            for (int mt = 0; mt < 2; mt++)
#pragma unroll
              for (int rr = 0; rr < 4; rr++) {
                int q = q0 + mt * 16 + g * 4 + rr;
#pragma unroll
                for (int nt = 0; nt < 4; nt++)
                  if (k0s + nt * 16 + c > q) sv[mt][nt][rr] = -1e30f;
              }
          }

#pragma unroll
          for (int mt = 0; mt < 2; mt++)
#pragma unroll
            for (int rr = 0; rr < 4; rr++) {
              union { u16x4 u; bf16x4 h; } pw;
#pragma unroll
              for (int nt = 0; nt < 4; nt++)
                pw.h[nt] = (__bf16)__builtin_amdgcn_exp2f(sv[mt][nt][rr]);
              *(u16x4*)&P[wid][mt * 16 + g * 4 + rr][4 * c] = pw.u;
            }

          asm volatile("s_waitcnt lgkmcnt(0)" ::: "memory");

#pragma unroll
          for (int mt = 0; mt < 2; mt++) {
            bf16x8 pf0 = *(const bf16x8*)&P[wid][mt * 16 + c][g * 8];
            bf16x8 pf1 = *(const bf16x8*)&P[wid][mt * 16 + c][32 + g * 8];
            lac[mt] = MFMA(pf0, ones, lac[mt]);
            lac[mt] = MFMA(pf1, ones, lac[mt]);
#pragma unroll
            for (int ot = 0; ot < 4; ot++) {
              f32x4 oo = MFMA(pf0, vf[ot][0], o[mt][ot]);
              o[mt][ot] = MFMA(pf1, vf[ot][1], oo);
            }
          }
        }
      }
      __syncthreads();
    }

    float inv[2][4];
#pragma unroll
    for (int mt = 0; mt < 2; mt++)
#pragma unroll
      for (int rr = 0; rr < 4; rr++) inv[mt][rr] = 1.0f / lac[mt][rr];
#pragma unroll
    for (int mt = 0; mt < 2; mt++)
#pragma unroll
      for (int ot = 0; ot < 4; ot++)
#pragma unroll
        for (int rr = 0; rr < 4; rr++) {
          int t = q0 + mt * 16 + g * 4 + rr;
          int hd = ot * 16 + c;
          size_t xi = ((size_t)b * 2048 + t) * 1024 + head * 64 + hd;
          float v = x[xi] + o[mt][ot][rr] * inv[mt][rr];
          x1[xi] = v;
          xb1[xi] = f2b(v);
        }
  }
}

// ---------------------------------------------------------------------------
extern "C" void kernel_launch(void* const* d_in, const int* in_sizes, int n_in,
                              void* d_out, int out_size, void* d_ws, size_t ws_size,
                              hipStream_t stream) {
  (void)in_sizes; (void)n_in; (void)out_size; (void)ws_size;
  const float* x = (const float*)d_in[0];
  const float* Wq = (const float*)d_in[1];
  const float* bq = (const float*)d_in[2];
  const float* Wk = (const float*)d_in[3];
  const float* bk = (const float*)d_in[4];
  const float* Wv = (const float*)d_in[5];
  const float* bv = (const float*)d_in[6];
  const float* W1 = (const float*)d_in[7];
  const float* b1 = (const float*)d_in[8];
  const float* W2 = (const float*)d_in[9];
  const float* b2 = (const float*)d_in[10];

  char* ws = (char*)d_ws;
  size_t off = 0;
  auto alloc = [&](size_t bytes) {
    char* p = ws + off;
    off += (bytes + 255) & ~(size_t)255;
    return p;
  };
  u16* xb    = (u16*)alloc(8192ull * 1024 * 2);   // bf16(x)
  u16* Wqkvt = (u16*)alloc(3072ull * 1024 * 2);   // [3072][1024] bf16 (Wq|Wk|Wv rows)
  u16* W1t   = (u16*)alloc(4096ull * 1024 * 2);
  u16* W2t   = (u16*)alloc(1024ull * 4096 * 2);
  u16* Qb    = (u16*)alloc(3ull * 8192 * 1024 * 2);  // Q|K|V frag-ordered, contiguous
  float* x1  = (float*)alloc(8192ull * 1024 * 4); // x + attn (fp32 residual)
  u16* hb    = (u16*)alloc(8192ull * 4096 * 2);   // gelu(x1@W1+b1)
  u16* xb1   = xb;  // xb dead after QKV gemm; reuse for bf16(x1)
  u16* Kb    = Qb + 8388608;
  u16* Vtb   = Qb + 16777216;

  const float qscale = 1.4426950408889634f / 32.0f;  // log2e / sqrt(H)

  // 1. x -> bf16
  xconv<<<dim3(8192), dim3(256), 0, stream>>>(x, xb, 8192 * 1024);
  // 2. all weight transposes in one launch
  wtrans_all<<<dim3(11264), dim3(32, 8), 0, stream>>>(
      Wq, Wk, Wv, W1, W2, Wqkvt, W1t, W2t);
  // 3. fused QKV projection (M=8192, N=3072, K=1024) -> frag-ordered Q/K/V
  //    R3-proven 256x128 3-buffer (acc=64: scatter epilogue fits registers)
  gemm256<4><<<dim3(768), dim3(512), 0, stream>>>(
      xb, Wqkvt, bq, bk, bv, Qb, nullptr, 3072, 1024, qscale);
  // 4. attention + residual 1  (512 blocks; paired 128-row tiles)
  attn_kernel<<<dim3(512), dim3(256), 0, stream>>>(Qb, Kb, Vtb, x, x1, xb1);
  // 5. MLP1: gelu(x1 @ W1 + b1): 256x256 8-phase counted (32 x 16 = 512 blocks)
  gemm8p<2><<<dim3(512), dim3(512), 0, stream>>>(
      xb1, W1t, b1, hb, 4096, 1024);
  // 6. MLP2 + residual 2 -> d_out (fp32) (M=8192, N=1024, K=4096): 32 x 8 = 256
  //    blocks = exactly 1 block/CU, one clean round, 64 K-tiles of pipeline.
  gemm256<3><<<dim3(256), dim3(512), 0, stream>>>(
      hb, W2t, b2, nullptr, nullptr, d_out, x1, 1024, 4096, 1.0f);
}